// Round 5
// baseline (517.749 us; speedup 1.0000x reference)
//
#include <hip/hip_runtime.h>
#include <hip/hip_bf16.h>

typedef __bf16 bf16x8 __attribute__((ext_vector_type(8)));
typedef float f32x4 __attribute__((ext_vector_type(4)));
typedef unsigned short u16x4 __attribute__((ext_vector_type(4)));
typedef unsigned short u16x8 __attribute__((ext_vector_type(8)));

#define EPS 1e-8f
#define TAU_INV 10.0f

#define BM 64
#define BN 512
#define BK 32
#define LSTRIDE 516              // 512 + 4 pad for epilogue fp32 tile
#define ABUF 2048                // u16 per A buffer: 64 rows * 32 k
#define GRID 512                 // persistent: 2 blocks per CU, phase-locked

__device__ __forceinline__ u16x4 cvt_bf16x4(f32x4 v) {
    u16x4 u;
    u[0] = __builtin_bit_cast(unsigned short, __float2bfloat16(v[0]));
    u[1] = __builtin_bit_cast(unsigned short, __float2bfloat16(v[1]));
    u[2] = __builtin_bit_cast(unsigned short, __float2bfloat16(v[2]));
    u[3] = __builtin_bit_cast(unsigned short, __float2bfloat16(v[3]));
    return u;
}

// non-temporal f32x4 load: A streams with evict-first policy (protects B in L2)
__device__ __forceinline__ f32x4 ldnt_f32x4(const float* p) {
    return __builtin_nontemporal_load((const f32x4*)p);
}

// ---------------------------------------------------------------------------
// prep: centers -> bf16 in MFMA-granule-swizzled order + inv norms.
// Bsw granule (kt,nt,q): 16B at ((kt*32 + nt)*64 + r16 + q*16)*8 u16,
// holding B[row][kt*32 + q*8 .. +8]. A wave's B fragment for (kt, nt) is the
// contiguous 1KB at ((kt*32+nt)*64 + lane)*8 -> coalesced global->VGPR loads.
// ---------------------------------------------------------------------------
__global__ __launch_bounds__(256) void prep_centers_kernel(
    const float* __restrict__ cen, unsigned short* __restrict__ Bsw,
    float* __restrict__ inv_c, int K, int D)
{
    const int wave = threadIdx.x >> 6;
    const int lane = threadIdx.x & 63;
    const int row  = blockIdx.x * 4 + wave;
    if (row >= K) return;

    const float* src = cen + (size_t)row * D + lane * 16;
    const int kt = lane >> 1;
    const int nt = row >> 4;
    const int r16 = row & 15;
    const int q0 = (lane & 1) * 2;

    float ss = 0.0f;
    u16x8 g[2];
    #pragma unroll
    for (int h = 0; h < 2; ++h) {
        #pragma unroll
        for (int j = 0; j < 2; ++j) {
            float4 v = *(const float4*)(src + h * 8 + j * 4);
            ss += v.x * v.x + v.y * v.y + v.z * v.z + v.w * v.w;
            g[h][j * 4 + 0] = __builtin_bit_cast(unsigned short, __float2bfloat16(v.x));
            g[h][j * 4 + 1] = __builtin_bit_cast(unsigned short, __float2bfloat16(v.y));
            g[h][j * 4 + 2] = __builtin_bit_cast(unsigned short, __float2bfloat16(v.z));
            g[h][j * 4 + 3] = __builtin_bit_cast(unsigned short, __float2bfloat16(v.w));
        }
        size_t off = ((size_t)(kt * 32 + nt) * 64 + r16 + (q0 + h) * 16) * 8;
        *(u16x8*)(Bsw + off) = g[h];
    }
    #pragma unroll
    for (int off = 32; off; off >>= 1) ss += __shfl_xor(ss, off);
    if (lane == 0)
        inv_c[row] = (1.0f / fmaxf(sqrtf(ss), EPS)) * TAU_INV; // fold 1/tau
}

// ---------------------------------------------------------------------------
// fused GEMM + log-softmax + NLL, PERSISTENT phase-locked, 2 blocks/CU.
// 512 blocks x 512 threads; each block does 2 row-tiles of 64.
// Phase-locked cohort keeps B L2-resident (round-4 counters: FETCH 135MB,
// B-refetch eliminated). 2 co-resident blocks/CU (4 waves/SIMD) so one
// block's barrier/latency stalls hide under the other's compute.
// Residency arithmetic: 4 waves/SIMD x 92 VGPR = 368 <= 512; LDS 2x33.7KB.
// __launch_bounds__(512,4) caps VGPR at 128 to guarantee it.
// ---------------------------------------------------------------------------
__global__ __launch_bounds__(512, 4) void gemm_loss_kernel(
    const float* __restrict__ Afp, const unsigned short* __restrict__ Bsw,
    const float* __restrict__ inv_c, const int* __restrict__ labels,
    float* __restrict__ out, int N, int D)
{
    __shared__ union {
        unsigned short t[2 * ABUF];    // A staging (8 KB)
        float L[16 * LSTRIDE];         // epilogue overlay (33 KB)
    } sm;
    __shared__ float inv_e_s[BM];
    __shared__ float blockLoss;

    const int tid  = threadIdx.x;
    const int wave = tid >> 6;
    const int lane = tid & 63;
    const int quad = lane >> 4;
    const int tq   = lane & 15;

    // ---- A staging map: thread owns (row=tid>>3, float4 slice aj=tid&7) ----
    const int ar   = tid >> 3;        // 0..63
    const int aj   = tid & 7;         // 0..7
    const int a_q  = aj >> 1, a_jl = aj & 1;
    const int a_r16 = ar & 15;
    const int a_woff = (ar >> 4) * 512 + ((a_r16 ^ (2 * a_q)) + a_q * 16) * 8 + a_jl * 4;

    // ---- B fragment base: wave's nt tiles are wave*4 + i (i=0..3) ----
    const unsigned short* bbase = Bsw + (size_t)(wave * 4) * 512 + lane * 8;

    // ---- A fragment read offsets (buffer-relative, kt-invariant) ----
    const int a_rslot = (tq ^ (2 * quad)) + quad * 16;
    int aro[4];
    #pragma unroll
    for (int mt = 0; mt < 4; ++mt) aro[mt] = mt * 512 + a_rslot * 8;

    float ic[4];
    #pragma unroll
    for (int nt = 0; nt < 4; ++nt)
        ic[nt] = inv_c[wave * 64 + nt * 16 + tq];
    const float invN = 1.0f / (float)N;

    if (tid == 0) blockLoss = 0.0f;

    const int nK = D / BK;               // 32
    const int nTiles = N / (BM * GRID);  // 2

    for (int t = 0; t < nTiles; ++t) {
        const size_t rowBase = (size_t)(t * GRID + blockIdx.x) * BM;
        const float* ag = Afp + (rowBase + ar) * D + aj * 4;

        f32x4 acc[4][4];
        #pragma unroll
        for (int mt = 0; mt < 4; ++mt)
            #pragma unroll
            for (int nt = 0; nt < 4; ++nt)
                acc[mt][nt] = (f32x4){0.f, 0.f, 0.f, 0.f};

        float ssq;
        f32x4 v1;
        bf16x8 bcur[4];

        // ---- prologue: stage A kt=0 into buf0; prefetch A kt=1, B kt=0 ----
        {
            f32x4 v0 = ldnt_f32x4(ag);
            v1 = ldnt_f32x4(ag + BK);
            #pragma unroll
            for (int i = 0; i < 4; ++i)
                bcur[i] = *(const bf16x8*)(bbase + i * 512);
            ssq = v0[0] * v0[0] + v0[1] * v0[1] + v0[2] * v0[2] + v0[3] * v0[3];
            *(u16x4*)&sm.t[a_woff] = cvt_bf16x4(v0);
        }

        for (int kt = 0; kt < nK; ++kt) {
            __syncthreads();   // buf[kt] staged & visible; buf[kt+1] free
            unsigned short* cur = &sm.t[(kt & 1) * ABUF];
            unsigned short* nxt = &sm.t[((kt + 1) & 1) * ABUF];
            const bool hn1 = (kt + 1) < nK;
            const bool hn2 = (kt + 2) < nK;

            f32x4 v2;
            if (hn2) v2 = ldnt_f32x4(ag + (kt + 2) * BK);   // A dist-2 prefetch

            bf16x8 bnxt[4];
            if (hn1) {                                       // B dist-1 prefetch
                const unsigned short* bn = bbase + (size_t)(kt + 1) * 16384;
                #pragma unroll
                for (int i = 0; i < 4; ++i)
                    bnxt[i] = *(const bf16x8*)(bn + i * 512);
            }

            bf16x8 af[4];
            #pragma unroll
            for (int mt = 0; mt < 4; ++mt) af[mt] = *(const bf16x8*)(cur + aro[mt]);

            if (hn1) {   // v1 issued a full step ago -> arrived; stage into nxt
                ssq += v1[0] * v1[0] + v1[1] * v1[1] + v1[2] * v1[2] + v1[3] * v1[3];
                *(u16x4*)(nxt + a_woff) = cvt_bf16x4(v1);
            }

            #pragma unroll
            for (int nt = 0; nt < 4; ++nt)
                #pragma unroll
                for (int mt = 0; mt < 4; ++mt)
                    acc[mt][nt] = __builtin_amdgcn_mfma_f32_16x16x32_bf16(
                        af[mt], bcur[nt], acc[mt][nt], 0, 0, 0);

            if (hn1) {
                #pragma unroll
                for (int i = 0; i < 4; ++i) bcur[i] = bnxt[i];
            }
            if (hn2) v1 = v2;
        }

        // ---- row inverse norms: reduce 8 k-slice partials per row ----
        ssq += __shfl_xor(ssq, 1);
        ssq += __shfl_xor(ssq, 2);
        ssq += __shfl_xor(ssq, 4);
        if (aj == 0) inv_e_s[ar] = 1.0f / fmaxf(sqrtf(ssq), EPS);

        // ---- epilogue: scale + per-16-row logsumexp + NLL ----
        for (int g = 0; g < 4; ++g) {
            __syncthreads();           // also makes inv_e_s visible (g=0)
            float ie[4];
            #pragma unroll
            for (int r = 0; r < 4; ++r)
                ie[r] = inv_e_s[g * 16 + quad * 4 + r];
            #pragma unroll
            for (int nt = 0; nt < 4; ++nt) {
                int col = wave * 64 + nt * 16 + tq;
                #pragma unroll
                for (int r = 0; r < 4; ++r)
                    sm.L[(quad * 4 + r) * LSTRIDE + col] = acc[g][nt][r] * ie[r] * ic[nt];
            }
            __syncthreads();
            #pragma unroll
            for (int rr = 0; rr < 2; ++rr) {
                int rl = wave * 2 + rr;
                size_t grow = rowBase + g * 16 + rl;
                float vals[8];
                float vmax = -3.0e38f;
                #pragma unroll
                for (int j = 0; j < 8; ++j) {
                    vals[j] = sm.L[rl * LSTRIDE + j * 64 + lane];
                    vmax = fmaxf(vmax, vals[j]);
                }
                #pragma unroll
                for (int off = 32; off; off >>= 1) vmax = fmaxf(vmax, __shfl_xor(vmax, off));
                float s = 0.0f;
                #pragma unroll
                for (int j = 0; j < 8; ++j) s += __expf(vals[j] - vmax);
                #pragma unroll
                for (int off = 32; off; off >>= 1) s += __shfl_xor(s, off);
                if (lane == 0) {
                    int lab = labels[grow];
                    float ll = sm.L[rl * LSTRIDE + lab];
                    atomicAdd(&blockLoss, vmax + __logf(s) - ll);
                }
            }
        }
        __syncthreads();   // L free for next tile's staging; orders blockLoss
    }

    if (tid == 0) atomicAdd(out, blockLoss * invN);
}

// ---------------------------------------------------------------------------
extern "C" void kernel_launch(void* const* d_in, const int* in_sizes, int n_in,
                              void* d_out, int out_size, void* d_ws, size_t ws_size,
                              hipStream_t stream)
{
    const float* emb = (const float*)d_in[0];
    const float* cen = (const float*)d_in[1];
    const int* labels = (const int*)d_in[2];
    float* out = (float*)d_out;

    const int N = in_sizes[2];
    const int D = in_sizes[0] / N;
    const int K = in_sizes[1] / D;

    char* ws = (char*)d_ws;
    unsigned short* Bsw = (unsigned short*)ws;              // K*D*2 bytes, swizzled
    float* inv_c = (float*)(ws + (size_t)K * D * 2);        // K floats

    hipMemsetAsync(d_out, 0, sizeof(float), stream);

    prep_centers_kernel<<<(K + 3) / 4, 256, 0, stream>>>(cen, Bsw, inv_c, K, D);

    gemm_loss_kernel<<<GRID, 512, 0, stream>>>(emb, Bsw, inv_c, labels, out, N, D);
}

// Round 6
// 413.670 us; speedup vs baseline: 1.2516x; 1.2516x over previous
//
#include <hip/hip_runtime.h>
#include <hip/hip_bf16.h>

typedef __bf16 bf16x8 __attribute__((ext_vector_type(8)));
typedef float f32x4 __attribute__((ext_vector_type(4)));
typedef unsigned short u16x4 __attribute__((ext_vector_type(4)));
typedef unsigned short u16x8 __attribute__((ext_vector_type(8)));

#define EPS 1e-8f
#define TAU_INV 10.0f

#define BM 64
#define BN 512
#define BK 32
#define LSTRIDE 516              // 512 + 4 pad for epilogue fp32 tile
#define ABUF 2048                // u16 per A buffer: 64 rows * 32 k
#define GRID 512                 // persistent: 2 blocks per CU, phase-locked

__device__ __forceinline__ u16x4 cvt_bf16x4(f32x4 v) {
    u16x4 u;
    u[0] = __builtin_bit_cast(unsigned short, __float2bfloat16(v[0]));
    u[1] = __builtin_bit_cast(unsigned short, __float2bfloat16(v[1]));
    u[2] = __builtin_bit_cast(unsigned short, __float2bfloat16(v[2]));
    u[3] = __builtin_bit_cast(unsigned short, __float2bfloat16(v[3]));
    return u;
}

// non-temporal f32x4 load: A streams with evict-first policy (protects B in L2)
__device__ __forceinline__ f32x4 ldnt_f32x4(const float* p) {
    return __builtin_nontemporal_load((const f32x4*)p);
}

// ---------------------------------------------------------------------------
// prep: centers -> bf16 in MFMA-granule-swizzled order + inv norms.
// Bsw granule (kt,nt,q): 16B at ((kt*32 + nt)*64 + r16 + q*16)*8 u16,
// holding B[row][kt*32 + q*8 .. +8]. A wave's B fragment for (kt, nt) is the
// contiguous 1KB at ((kt*32+nt)*64 + lane)*8 -> coalesced global->VGPR loads.
// ---------------------------------------------------------------------------
__global__ __launch_bounds__(256) void prep_centers_kernel(
    const float* __restrict__ cen, unsigned short* __restrict__ Bsw,
    float* __restrict__ inv_c, int K, int D)
{
    const int wave = threadIdx.x >> 6;
    const int lane = threadIdx.x & 63;
    const int row  = blockIdx.x * 4 + wave;
    if (row >= K) return;

    const float* src = cen + (size_t)row * D + lane * 16;
    const int kt = lane >> 1;
    const int nt = row >> 4;
    const int r16 = row & 15;
    const int q0 = (lane & 1) * 2;

    float ss = 0.0f;
    u16x8 g[2];
    #pragma unroll
    for (int h = 0; h < 2; ++h) {
        #pragma unroll
        for (int j = 0; j < 2; ++j) {
            float4 v = *(const float4*)(src + h * 8 + j * 4);
            ss += v.x * v.x + v.y * v.y + v.z * v.z + v.w * v.w;
            g[h][j * 4 + 0] = __builtin_bit_cast(unsigned short, __float2bfloat16(v.x));
            g[h][j * 4 + 1] = __builtin_bit_cast(unsigned short, __float2bfloat16(v.y));
            g[h][j * 4 + 2] = __builtin_bit_cast(unsigned short, __float2bfloat16(v.z));
            g[h][j * 4 + 3] = __builtin_bit_cast(unsigned short, __float2bfloat16(v.w));
        }
        size_t off = ((size_t)(kt * 32 + nt) * 64 + r16 + (q0 + h) * 16) * 8;
        *(u16x8*)(Bsw + off) = g[h];
    }
    #pragma unroll
    for (int off = 32; off; off >>= 1) ss += __shfl_xor(ss, off);
    if (lane == 0)
        inv_c[row] = (1.0f / fmaxf(sqrtf(ss), EPS)) * TAU_INV; // fold 1/tau
}

// ---------------------------------------------------------------------------
// fused GEMM + log-softmax + NLL, PERSISTENT phase-locked, 2 blocks/CU.
// 512 blocks x 512 threads; each block does 2 row-tiles of 64.
// Register budget engineered for 2-block residency at the 128-VGPR cap:
// acc 64 + af 16 + one in-flight B frag 4 + step-local A vec 4 + addr ~15.
// (Round-5 lesson: bnxt[4]+v2 prefetch regs blew the cap -> 89MB scratch
// spill. B's L2 latency is covered by TLP (4 waves/SIMD) instead of regs.)
// ---------------------------------------------------------------------------
__global__ __launch_bounds__(512, 4) void gemm_loss_kernel(
    const float* __restrict__ Afp, const unsigned short* __restrict__ Bsw,
    const float* __restrict__ inv_c, const int* __restrict__ labels,
    float* __restrict__ out, int N, int D)
{
    __shared__ union {
        unsigned short t[2 * ABUF];    // A staging (8 KB)
        float L[16 * LSTRIDE];         // epilogue overlay (33 KB)
    } sm;
    __shared__ float inv_e_s[BM];
    __shared__ float blockLoss;

    const int tid  = threadIdx.x;
    const int wave = tid >> 6;
    const int lane = tid & 63;
    const int quad = lane >> 4;
    const int tq   = lane & 15;

    // ---- A staging map: thread owns (row=tid>>3, float4 slice aj=tid&7) ----
    const int ar   = tid >> 3;        // 0..63
    const int aj   = tid & 7;         // 0..7
    const int a_q  = aj >> 1, a_jl = aj & 1;
    const int a_r16 = ar & 15;
    const int a_woff = (ar >> 4) * 512 + ((a_r16 ^ (2 * a_q)) + a_q * 16) * 8 + a_jl * 4;

    // ---- B fragment base: wave's nt tiles are wave*4 + i (i=0..3) ----
    const unsigned short* bbase = Bsw + (size_t)(wave * 4) * 512 + lane * 8;

    // ---- A fragment read offset (buffer-relative, kt-invariant) ----
    const int a_rbase = ((tq ^ (2 * quad)) + quad * 16) * 8;

    const float invN = 1.0f / (float)N;
    if (tid == 0) blockLoss = 0.0f;

    const int nK = D / BK;               // 32
    const int nTiles = N / (BM * GRID);  // 2

    for (int t = 0; t < nTiles; ++t) {
        const size_t rowBase = (size_t)(t * GRID + blockIdx.x) * BM;
        const float* ag = Afp + (rowBase + ar) * D + aj * 4;

        f32x4 acc[4][4];
        #pragma unroll
        for (int mt = 0; mt < 4; ++mt)
            #pragma unroll
            for (int nt = 0; nt < 4; ++nt)
                acc[mt][nt] = (f32x4){0.f, 0.f, 0.f, 0.f};

        float ssq;

        // ---- prologue: stage A kt=0 into buf0 ----
        {
            f32x4 v0 = ldnt_f32x4(ag);
            ssq = v0[0] * v0[0] + v0[1] * v0[1] + v0[2] * v0[2] + v0[3] * v0[3];
            *(u16x4*)&sm.t[a_woff] = cvt_bf16x4(v0);
        }

        for (int kt = 0; kt < nK; ++kt) {
            __syncthreads();   // buf[kt] staged & visible; buf[kt+1] free
            unsigned short* cur = &sm.t[(kt & 1) * ABUF];
            unsigned short* nxt = &sm.t[((kt + 1) & 1) * ABUF];
            const bool hn = (kt + 1) < nK;

            // A dist-1 prefetch, step-local: issued here, consumed ~300+ cyc
            // later at the end-of-step LDS write -> latency hidden, no
            // loop-carried register.
            f32x4 v1;
            if (hn) v1 = ldnt_f32x4(ag + (kt + 1) * BK);

            bf16x8 af[4];
            #pragma unroll
            for (int mt = 0; mt < 4; ++mt)
                af[mt] = *(const bf16x8*)(cur + mt * 512 + a_rbase);

            // B fragments loaded per-nt (<= a couple in flight): L2-resident,
            // latency covered by sibling waves' MFMAs (4 waves/SIMD).
            const unsigned short* bk = bbase + (size_t)kt * 16384;
            #pragma unroll
            for (int nt = 0; nt < 4; ++nt) {
                bf16x8 bf = *(const bf16x8*)(bk + nt * 512);
                #pragma unroll
                for (int mt = 0; mt < 4; ++mt)
                    acc[mt][nt] = __builtin_amdgcn_mfma_f32_16x16x32_bf16(
                        af[mt], bf, acc[mt][nt], 0, 0, 0);
            }

            if (hn) {
                ssq += v1[0] * v1[0] + v1[1] * v1[1] + v1[2] * v1[2] + v1[3] * v1[3];
                *(u16x4*)(nxt + a_woff) = cvt_bf16x4(v1);
            }
        }

        // ---- row inverse norms: reduce 8 k-slice partials per row ----
        ssq += __shfl_xor(ssq, 1);
        ssq += __shfl_xor(ssq, 2);
        ssq += __shfl_xor(ssq, 4);
        if (aj == 0) inv_e_s[ar] = 1.0f / fmaxf(sqrtf(ssq), EPS);

        // ---- epilogue: scale + per-16-row logsumexp + NLL ----
        float ic[4];
        #pragma unroll
        for (int nt = 0; nt < 4; ++nt)
            ic[nt] = inv_c[wave * 64 + nt * 16 + tq];

        for (int g = 0; g < 4; ++g) {
            __syncthreads();           // also makes inv_e_s visible (g=0)
            float ie[4];
            #pragma unroll
            for (int r = 0; r < 4; ++r)
                ie[r] = inv_e_s[g * 16 + quad * 4 + r];
            #pragma unroll
            for (int nt = 0; nt < 4; ++nt) {
                int col = wave * 64 + nt * 16 + tq;
                #pragma unroll
                for (int r = 0; r < 4; ++r)
                    sm.L[(quad * 4 + r) * LSTRIDE + col] = acc[g][nt][r] * ie[r] * ic[nt];
            }
            __syncthreads();
            #pragma unroll
            for (int rr = 0; rr < 2; ++rr) {
                int rl = wave * 2 + rr;
                size_t grow = rowBase + g * 16 + rl;
                float vals[8];
                float vmax = -3.0e38f;
                #pragma unroll
                for (int j = 0; j < 8; ++j) {
                    vals[j] = sm.L[rl * LSTRIDE + j * 64 + lane];
                    vmax = fmaxf(vmax, vals[j]);
                }
                #pragma unroll
                for (int off = 32; off; off >>= 1) vmax = fmaxf(vmax, __shfl_xor(vmax, off));
                float s = 0.0f;
                #pragma unroll
                for (int j = 0; j < 8; ++j) s += __expf(vals[j] - vmax);
                #pragma unroll
                for (int off = 32; off; off >>= 1) s += __shfl_xor(s, off);
                if (lane == 0) {
                    int lab = labels[grow];
                    float ll = sm.L[rl * LSTRIDE + lab];
                    atomicAdd(&blockLoss, vmax + __logf(s) - ll);
                }
            }
        }
        __syncthreads();   // L free for next tile's staging; orders blockLoss
    }

    if (tid == 0) atomicAdd(out, blockLoss * invN);
}

// ---------------------------------------------------------------------------
extern "C" void kernel_launch(void* const* d_in, const int* in_sizes, int n_in,
                              void* d_out, int out_size, void* d_ws, size_t ws_size,
                              hipStream_t stream)
{
    const float* emb = (const float*)d_in[0];
    const float* cen = (const float*)d_in[1];
    const int* labels = (const int*)d_in[2];
    float* out = (float*)d_out;

    const int N = in_sizes[2];
    const int D = in_sizes[0] / N;
    const int K = in_sizes[1] / D;

    char* ws = (char*)d_ws;
    unsigned short* Bsw = (unsigned short*)ws;              // K*D*2 bytes, swizzled
    float* inv_c = (float*)(ws + (size_t)K * D * 2);        // K floats

    hipMemsetAsync(d_out, 0, sizeof(float), stream);

    prep_centers_kernel<<<(K + 3) / 4, 256, 0, stream>>>(cen, Bsw, inv_c, K, D);

    gemm_loss_kernel<<<GRID, 512, 0, stream>>>(emb, Bsw, inv_c, labels, out, N, D);
}

// Round 7
// 407.712 us; speedup vs baseline: 1.2699x; 1.0146x over previous
//
#include <hip/hip_runtime.h>
#include <hip/hip_bf16.h>

typedef __bf16 bf16x8 __attribute__((ext_vector_type(8)));
typedef float f32x4 __attribute__((ext_vector_type(4)));
typedef unsigned short u16x4 __attribute__((ext_vector_type(4)));
typedef unsigned short u16x8 __attribute__((ext_vector_type(8)));

#define EPS 1e-8f
#define TAU_INV 10.0f

#define BM 64
#define BN 512
#define BK 32
#define LSTRIDE 516              // 512 + 4 pad for epilogue fp32 tile
#define ABUF 2048                // u16 per A buffer: 64 rows * 32 k
#define GRID 512                 // persistent: 2 blocks per CU, phase-locked

__device__ __forceinline__ u16x4 cvt_bf16x4(f32x4 v) {
    u16x4 u;
    u[0] = __builtin_bit_cast(unsigned short, __float2bfloat16(v[0]));
    u[1] = __builtin_bit_cast(unsigned short, __float2bfloat16(v[1]));
    u[2] = __builtin_bit_cast(unsigned short, __float2bfloat16(v[2]));
    u[3] = __builtin_bit_cast(unsigned short, __float2bfloat16(v[3]));
    return u;
}

// non-temporal f32x4 load: A streams with evict-first policy (protects B in L2)
__device__ __forceinline__ f32x4 ldnt_f32x4(const float* p) {
    return __builtin_nontemporal_load((const f32x4*)p);
}

// ---------------------------------------------------------------------------
// prep: centers -> bf16 in MFMA-granule-swizzled order + inv norms.
// Bsw granule (kt,nt,q): 16B at ((kt*32 + nt)*64 + r16 + q*16)*8 u16,
// holding B[row][kt*32 + q*8 .. +8]. A wave's B fragment for (kt, nt) is the
// contiguous 1KB at ((kt*32+nt)*64 + lane)*8 -> coalesced global->VGPR loads.
// ---------------------------------------------------------------------------
__global__ __launch_bounds__(256) void prep_centers_kernel(
    const float* __restrict__ cen, unsigned short* __restrict__ Bsw,
    float* __restrict__ inv_c, int K, int D)
{
    const int wave = threadIdx.x >> 6;
    const int lane = threadIdx.x & 63;
    const int row  = blockIdx.x * 4 + wave;
    if (row >= K) return;

    const float* src = cen + (size_t)row * D + lane * 16;
    const int kt = lane >> 1;
    const int nt = row >> 4;
    const int r16 = row & 15;
    const int q0 = (lane & 1) * 2;

    float ss = 0.0f;
    u16x8 g[2];
    #pragma unroll
    for (int h = 0; h < 2; ++h) {
        #pragma unroll
        for (int j = 0; j < 2; ++j) {
            float4 v = *(const float4*)(src + h * 8 + j * 4);
            ss += v.x * v.x + v.y * v.y + v.z * v.z + v.w * v.w;
            g[h][j * 4 + 0] = __builtin_bit_cast(unsigned short, __float2bfloat16(v.x));
            g[h][j * 4 + 1] = __builtin_bit_cast(unsigned short, __float2bfloat16(v.y));
            g[h][j * 4 + 2] = __builtin_bit_cast(unsigned short, __float2bfloat16(v.z));
            g[h][j * 4 + 3] = __builtin_bit_cast(unsigned short, __float2bfloat16(v.w));
        }
        size_t off = ((size_t)(kt * 32 + nt) * 64 + r16 + (q0 + h) * 16) * 8;
        *(u16x8*)(Bsw + off) = g[h];
    }
    #pragma unroll
    for (int off = 32; off; off >>= 1) ss += __shfl_xor(ss, off);
    if (lane == 0)
        inv_c[row] = (1.0f / fmaxf(sqrtf(ss), EPS)) * TAU_INV; // fold 1/tau
}

// ---------------------------------------------------------------------------
// fused GEMM + log-softmax + NLL, PERSISTENT phase-locked, 2 blocks/CU.
// 512 blocks x 512 threads; each block does 2 row-tiles of 64.
//
// KEY ORDERING (round-7 fix): vmcnt is a FIFO. If the A HBM prefetch is
// issued before the B fragment loads, the MFMA block's counted wait for B
// transitively waits ~900cyc for A -> every K-step pays full HBM latency
// (all prior ~130us variants shared this). So per step we issue:
//   1) B fragment loads (L2, ~300cyc)  -- OLDEST in FIFO
//   2) af ds_reads (lgkmcnt, independent counter)
//   3) A dist-1 prefetch (HBM, ~900cyc) -- NEWEST
//   4) MFMAs: wait vmcnt(1) = B only; A latency runs under MFMA+convert,
//      consumed at the end-of-step ds_write.
// Register budget: acc 64 + af 16 + bfv 16 + v1 4 + addr ~15 = ~115 <= 128.
// ---------------------------------------------------------------------------
__global__ __launch_bounds__(512, 4) void gemm_loss_kernel(
    const float* __restrict__ Afp, const unsigned short* __restrict__ Bsw,
    const float* __restrict__ inv_c, const int* __restrict__ labels,
    float* __restrict__ out, int N, int D)
{
    __shared__ union {
        unsigned short t[2 * ABUF];    // A staging (8 KB)
        float L[16 * LSTRIDE];         // epilogue overlay (33 KB)
    } sm;
    __shared__ float inv_e_s[BM];
    __shared__ float blockLoss;

    const int tid  = threadIdx.x;
    const int wave = tid >> 6;
    const int lane = tid & 63;
    const int quad = lane >> 4;
    const int tq   = lane & 15;

    // ---- A staging map: thread owns (row=tid>>3, float4 slice aj=tid&7) ----
    const int ar   = tid >> 3;        // 0..63
    const int aj   = tid & 7;         // 0..7
    const int a_q  = aj >> 1, a_jl = aj & 1;
    const int a_r16 = ar & 15;
    const int a_woff = (ar >> 4) * 512 + ((a_r16 ^ (2 * a_q)) + a_q * 16) * 8 + a_jl * 4;

    // ---- B fragment base: wave's nt tiles are wave*4 + i (i=0..3) ----
    const unsigned short* bbase = Bsw + (size_t)(wave * 4) * 512 + lane * 8;

    // ---- A fragment read offset (buffer-relative, kt-invariant) ----
    const int a_rbase = ((tq ^ (2 * quad)) + quad * 16) * 8;

    const float invN = 1.0f / (float)N;
    if (tid == 0) blockLoss = 0.0f;

    const int nK = D / BK;               // 32
    const int nTiles = N / (BM * GRID);  // 2

    for (int t = 0; t < nTiles; ++t) {
        const size_t rowBase = (size_t)(t * GRID + blockIdx.x) * BM;
        const float* ag = Afp + (rowBase + ar) * D + aj * 4;

        f32x4 acc[4][4];
        #pragma unroll
        for (int mt = 0; mt < 4; ++mt)
            #pragma unroll
            for (int nt = 0; nt < 4; ++nt)
                acc[mt][nt] = (f32x4){0.f, 0.f, 0.f, 0.f};

        float ssq;

        // ---- prologue: stage A kt=0 into buf0 ----
        {
            f32x4 v0 = ldnt_f32x4(ag);
            ssq = v0[0] * v0[0] + v0[1] * v0[1] + v0[2] * v0[2] + v0[3] * v0[3];
            *(u16x4*)&sm.t[a_woff] = cvt_bf16x4(v0);
        }

        for (int kt = 0; kt < nK; ++kt) {
            __syncthreads();   // buf[kt] staged & visible; buf[kt+1] free
            unsigned short* cur = &sm.t[(kt & 1) * ABUF];
            unsigned short* nxt = &sm.t[((kt + 1) & 1) * ABUF];
            const bool hn = (kt + 1) < nK;

            // (1) B fragment loads FIRST -> oldest in vmcnt FIFO; the MFMA
            //     wait for these does NOT include the A HBM load below.
            bf16x8 bfv[4];
            const unsigned short* bk = bbase + (size_t)kt * 16384;
            #pragma unroll
            for (int i = 0; i < 4; ++i)
                bfv[i] = *(const bf16x8*)(bk + i * 512);

            // (2) A fragments from LDS (lgkmcnt, independent of vmcnt)
            bf16x8 af[4];
            #pragma unroll
            for (int mt = 0; mt < 4; ++mt)
                af[mt] = *(const bf16x8*)(cur + mt * 512 + a_rbase);

            // (3) A dist-1 prefetch LAST: consumed only at the end-of-step
            //     ds_write -> ~900cyc HBM latency hidden under the MFMAs.
            f32x4 v1;
            if (hn) v1 = ldnt_f32x4(ag + (kt + 1) * BK);

            // (4) MFMA block: waits only on B (+af via lgkmcnt)
            #pragma unroll
            for (int nt = 0; nt < 4; ++nt)
                #pragma unroll
                for (int mt = 0; mt < 4; ++mt)
                    acc[mt][nt] = __builtin_amdgcn_mfma_f32_16x16x32_bf16(
                        af[mt], bfv[nt], acc[mt][nt], 0, 0, 0);

            if (hn) {
                ssq += v1[0] * v1[0] + v1[1] * v1[1] + v1[2] * v1[2] + v1[3] * v1[3];
                *(u16x4*)(nxt + a_woff) = cvt_bf16x4(v1);
            }
        }

        // ---- row inverse norms: reduce 8 k-slice partials per row ----
        ssq += __shfl_xor(ssq, 1);
        ssq += __shfl_xor(ssq, 2);
        ssq += __shfl_xor(ssq, 4);
        if (aj == 0) inv_e_s[ar] = 1.0f / fmaxf(sqrtf(ssq), EPS);

        // ---- epilogue: scale + per-16-row logsumexp + NLL ----
        float ic[4];
        #pragma unroll
        for (int nt = 0; nt < 4; ++nt)
            ic[nt] = inv_c[wave * 64 + nt * 16 + tq];

        for (int g = 0; g < 4; ++g) {
            __syncthreads();           // also makes inv_e_s visible (g=0)
            float ie[4];
            #pragma unroll
            for (int r = 0; r < 4; ++r)
                ie[r] = inv_e_s[g * 16 + quad * 4 + r];
            #pragma unroll
            for (int nt = 0; nt < 4; ++nt) {
                int col = wave * 64 + nt * 16 + tq;
                #pragma unroll
                for (int r = 0; r < 4; ++r)
                    sm.L[(quad * 4 + r) * LSTRIDE + col] = acc[g][nt][r] * ie[r] * ic[nt];
            }
            __syncthreads();
            #pragma unroll
            for (int rr = 0; rr < 2; ++rr) {
                int rl = wave * 2 + rr;
                size_t grow = rowBase + g * 16 + rl;
                float vals[8];
                float vmax = -3.0e38f;
                #pragma unroll
                for (int j = 0; j < 8; ++j) {
                    vals[j] = sm.L[rl * LSTRIDE + j * 64 + lane];
                    vmax = fmaxf(vmax, vals[j]);
                }
                #pragma unroll
                for (int off = 32; off; off >>= 1) vmax = fmaxf(vmax, __shfl_xor(vmax, off));
                float s = 0.0f;
                #pragma unroll
                for (int j = 0; j < 8; ++j) s += __expf(vals[j] - vmax);
                #pragma unroll
                for (int off = 32; off; off >>= 1) s += __shfl_xor(s, off);
                if (lane == 0) {
                    int lab = labels[grow];
                    float ll = sm.L[rl * LSTRIDE + lab];
                    atomicAdd(&blockLoss, vmax + __logf(s) - ll);
                }
            }
        }
        __syncthreads();   // L free for next tile's staging; orders blockLoss
    }

    if (tid == 0) atomicAdd(out, blockLoss * invN);
}

// ---------------------------------------------------------------------------
extern "C" void kernel_launch(void* const* d_in, const int* in_sizes, int n_in,
                              void* d_out, int out_size, void* d_ws, size_t ws_size,
                              hipStream_t stream)
{
    const float* emb = (const float*)d_in[0];
    const float* cen = (const float*)d_in[1];
    const int* labels = (const int*)d_in[2];
    float* out = (float*)d_out;

    const int N = in_sizes[2];
    const int D = in_sizes[0] / N;
    const int K = in_sizes[1] / D;

    char* ws = (char*)d_ws;
    unsigned short* Bsw = (unsigned short*)ws;              // K*D*2 bytes, swizzled
    float* inv_c = (float*)(ws + (size_t)K * D * 2);        // K floats

    hipMemsetAsync(d_out, 0, sizeof(float), stream);

    prep_centers_kernel<<<(K + 3) / 4, 256, 0, stream>>>(cen, Bsw, inv_c, K, D);

    gemm_loss_kernel<<<GRID, 512, 0, stream>>>(emb, Bsw, inv_c, labels, out, N, D);
}